// Round 7
// baseline (882.280 us; speedup 1.0000x reference)
//
#include <hip/hip_runtime.h>
#include <hip/hip_bf16.h>

#define N_NODES 50000
#define N_EDGES 800000
#define HEADS 8
#define DIM 128
#define NEG_SLOPE 0.2f
#define EPS 1e-16f
#define NBUCK 391            // ceil(50000/128) buckets of 128 dst nodes
#define BCAP 2432            // bucket capacity; bucket load ~Poisson(2048), 8.5-sigma tail
#define NQ (N_EDGES / 4)     // 200000 edge quartets

// bf16x2 pack/unpack (RNE), exact unpack
__device__ inline unsigned int f2_to_bf2(float a, float b) {
    unsigned int ua = __float_as_uint(a);
    unsigned int ub = __float_as_uint(b);
    ua += 0x7fff + ((ua >> 16) & 1);
    ub += 0x7fff + ((ub >> 16) & 1);
    return (ua >> 16) | (ub & 0xffff0000u);
}
__device__ inline float2 bf2_to_f2(unsigned int u) {
    return make_float2(__uint_as_float(u << 16),
                       __uint_as_float(u & 0xffff0000u));
}

// ---------------------------------------------------------------------------
// Fused GEMM + bucket-binning.
//  Binning: LDS histogram of the block's 1024 edges over 391 buckets
//  (rank via LDS atomic), ONE global atomic per non-empty bucket to reserve
//  a contiguous range (latency hides under the k-loop), block's records for
//  a bucket stored at consecutive positions (partial store coalescing).
//  GEMM epilogue unchanged: per-node logits + bf16 h pack.
// ---------------------------------------------------------------------------
__global__ __launch_bounds__(256) void k_gemm_bin(const float* __restrict__ x,
                                                  const float* __restrict__ W,
                                                  const float* __restrict__ att_s,
                                                  const float* __restrict__ att_d,
                                                  const int* __restrict__ ei,
                                                  unsigned int* __restrict__ h_bf,
                                                  float* __restrict__ asrc,
                                                  float* __restrict__ adst,
                                                  int* __restrict__ cnt,
                                                  unsigned int* __restrict__ bin) {
    constexpr int LDT = 68;
    __shared__ float xs[128 * LDT];      // 34816 B
    __shared__ int ldsHist[NBUCK];
    __shared__ int ldsBase[NBUCK];
    const int row0 = blockIdx.x * 64;
    const int tid = threadIdx.x;

    // zero LDS histogram
    for (int b = tid; b < NBUCK; b += 256) ldsHist[b] = 0;

    // load 4 edges
    const int et = blockIdx.x * 256 + tid;
    int4 s4, d4;
    const bool act = (et < NQ);
    if (act) {
        s4 = ((const int4*)ei)[et];
        d4 = ((const int4*)(ei + N_EDGES))[et];
    }

    // stage x tile (transposed)
    for (int i = tid; i < 64 * 32; i += 256) {
        const int r = i >> 5;
        const int k4 = i & 31;
        const int row = row0 + r;
        float4 v = make_float4(0.f, 0.f, 0.f, 0.f);
        if (row < N_NODES) v = ((const float4*)x)[row * 32 + k4];
        const int k = k4 * 4;
        xs[(k + 0) * LDT + r] = v.x;
        xs[(k + 1) * LDT + r] = v.y;
        xs[(k + 2) * LDT + r] = v.z;
        xs[(k + 3) * LDT + r] = v.w;
    }
    __syncthreads();   // hist zeroed, xs staged

    // LDS ranks within (block, bucket)
    int b0 = 0, b1 = 0, b2 = 0, b3 = 0, r0 = 0, r1 = 0, r2 = 0, r3 = 0;
    if (act) {
        b0 = d4.x >> 7; b1 = d4.y >> 7; b2 = d4.z >> 7; b3 = d4.w >> 7;
        r0 = atomicAdd(&ldsHist[b0], 1);
        r1 = atomicAdd(&ldsHist[b1], 1);
        r2 = atomicAdd(&ldsHist[b2], 1);
        r3 = atomicAdd(&ldsHist[b3], 1);
    }
    __syncthreads();

    // reserve global ranges: one atomic per non-empty bucket
    for (int b = tid; b < NBUCK; b += 256) {
        const int c = ldsHist[b];
        if (c > 0) ldsBase[b] = atomicAdd(&cnt[b], c);
    }
    __syncthreads();

    // ---- GEMM k-loop (atomic returns drain underneath) ----
    const int colg = tid & 31;
    const int rowg = tid >> 5;
    float acc[8][4];
#pragma unroll
    for (int r = 0; r < 8; ++r)
#pragma unroll
        for (int j = 0; j < 4; ++j) acc[r][j] = 0.f;

    for (int k = 0; k < 128; ++k) {
        const float4 w = ((const float4*)W)[k * 32 + colg];
        const float* xr = xs + k * LDT + rowg * 8;
        const float4 xa = *(const float4*)(xr);
        const float4 xb = *(const float4*)(xr + 4);
        const float xv[8] = {xa.x, xa.y, xa.z, xa.w, xb.x, xb.y, xb.z, xb.w};
        const float wv[4] = {w.x, w.y, w.z, w.w};
#pragma unroll
        for (int r = 0; r < 8; ++r)
#pragma unroll
            for (int j = 0; j < 4; ++j) acc[r][j] += xv[r] * wv[j];
    }

    // ---- epilogue: logits + bf16 pack ----
    const int hd = colg >> 2;
    const float4 asv = ((const float4*)att_s)[colg];
    const float4 adv = ((const float4*)att_d)[colg];
#pragma unroll
    for (int r = 0; r < 8; ++r) {
        const int row = row0 + rowg * 8 + r;
        float ps = acc[r][0] * asv.x + acc[r][1] * asv.y +
                   acc[r][2] * asv.z + acc[r][3] * asv.w;
        float pd = acc[r][0] * adv.x + acc[r][1] * adv.y +
                   acc[r][2] * adv.z + acc[r][3] * adv.w;
        ps += __shfl_xor(ps, 1); ps += __shfl_xor(ps, 2);
        pd += __shfl_xor(pd, 1); pd += __shfl_xor(pd, 2);
        if (row < N_NODES) {
            if ((colg & 3) == 0) {
                asrc[row * 8 + hd] = ps;
                adst[row * 8 + hd] = pd;
            }
            uint2 p;
            p.x = f2_to_bf2(acc[r][0], acc[r][1]);
            p.y = f2_to_bf2(acc[r][2], acc[r][3]);
            ((uint2*)h_bf)[row * 32 + colg] = p;
        }
    }

    // ---- place records: (dlocal<<16)|src at reserved positions ----
    if (act) {
        const int p0 = ldsBase[b0] + r0;
        const int p1 = ldsBase[b1] + r1;
        const int p2 = ldsBase[b2] + r2;
        const int p3 = ldsBase[b3] + r3;
        if (p0 < BCAP) bin[b0 * BCAP + p0] = ((unsigned)(d4.x & 127) << 16) | (unsigned)s4.x;
        if (p1 < BCAP) bin[b1 * BCAP + p1] = ((unsigned)(d4.y & 127) << 16) | (unsigned)s4.y;
        if (p2 < BCAP) bin[b2 * BCAP + p2] = ((unsigned)(d4.z & 127) << 16) | (unsigned)s4.z;
        if (p3 < BCAP) bin[b3 * BCAP + p3] = ((unsigned)(d4.w & 127) << 16) | (unsigned)s4.w;
    }
}

// ---------------------------------------------------------------------------
// Bucket-resident aggregation. One block (8 waves) per 128-node bucket.
// acc[128][128] fp32 + den[128][8] + adst tile in LDS (~72 KB, 2 blocks/CU).
// Waves stream the bucket's edge records (wave-uniform uint4 loads, 4 edges/
// iter): gather h_bf[src] (coalesced 256B) + asrc[src], ex = exp(lrelu(.)),
// accumulate via LDS f32 atomics. Epilogue: self-loop, normalize, bias, ELU,
// one coalesced out write per node.
// ---------------------------------------------------------------------------
__global__ __launch_bounds__(512) void k_aggr_lds(const unsigned int* __restrict__ h_bf,
                                                  const unsigned int* __restrict__ bin,
                                                  const int* __restrict__ cnt,
                                                  const float* __restrict__ asrc,
                                                  const float* __restrict__ adst,
                                                  const float* __restrict__ bias,
                                                  float* __restrict__ out) {
    __shared__ float accS[128 * 128];   // 64 KB
    __shared__ float denS[128 * 8];     // 4 KB
    __shared__ float adstS[128 * 8];    // 4 KB

    const int bkt = blockIdx.x;
    const int tid = threadIdx.x;
    const int wid = tid >> 6;           // 0..7
    const int lane = tid & 63;
    const int hd = lane >> 3;

    for (int i = tid; i < 128 * 128; i += 512) accS[i] = 0.f;
    for (int i = tid; i < 128 * 8; i += 512) {
        denS[i] = 0.f;
        const int d = bkt * 128 + (i >> 3);
        adstS[i] = (d < N_NODES) ? adst[d * 8 + (i & 7)] : 0.f;
    }
    __syncthreads();

    const int cntb = min(cnt[bkt], BCAP);
    const unsigned int* seg = bin + bkt * BCAP;

    // 8 waves × 4 edges per iteration
    for (int e0 = wid * 4; e0 < cntb; e0 += 32) {
        const uint4 pk = *(const uint4*)(seg + e0);    // wave-uniform (may overread ≤3, in-ws)
        int s[4], dl[4];
        s[0] = pk.x & 0xffff; dl[0] = (pk.x >> 16) & 127;
        s[1] = pk.y & 0xffff; dl[1] = (pk.y >> 16) & 127;
        s[2] = pk.z & 0xffff; dl[2] = (pk.z >> 16) & 127;
        s[3] = pk.w & 0xffff; dl[3] = (pk.w >> 16) & 127;

        unsigned int hv[4];
        float a[4];
#pragma unroll
        for (int i = 0; i < 4; ++i) {
            hv[i] = h_bf[s[i] * 64 + lane];   // coalesced 256B per edge; tail garbage stays in-ws
            a[i] = asrc[s[i] * 8 + hd];
        }
#pragma unroll
        for (int i = 0; i < 4; ++i) {
            if (e0 + i < cntb) {
                float e = a[i] + adstS[dl[i] * 8 + hd];
                e = (e >= 0.f) ? e : NEG_SLOPE * e;
                const float ex = __expf(e);
                const float2 hv2 = bf2_to_f2(hv[i]);
                atomicAdd(&accS[dl[i] * 128 + 2 * lane], ex * hv2.x);
                atomicAdd(&accS[dl[i] * 128 + 2 * lane + 1], ex * hv2.y);
                if ((lane & 7) == 0) atomicAdd(&denS[dl[i] * 8 + hd], ex);
            }
        }
    }
    __syncthreads();

    // epilogue: 16 nodes per wave
    for (int dl = wid; dl < 128; dl += 8) {
        const int d = bkt * 128 + dl;
        if (d >= N_NODES) continue;
        const float ad = adstS[dl * 8 + hd];
        const float as = asrc[d * 8 + hd];
        float es = as + ad;
        es = (es >= 0.f) ? es : NEG_SLOPE * es;
        const float exs = __expf(es);
        const float2 hdv = bf2_to_f2(h_bf[d * 64 + lane]);
        const float dtot = denS[dl * 8 + hd] + exs + EPS;
        const float2 b2 = ((const float2*)bias)[lane];
        float vx = (accS[dl * 128 + 2 * lane] + exs * hdv.x) / dtot + b2.x;
        float vy = (accS[dl * 128 + 2 * lane + 1] + exs * hdv.y) / dtot + b2.y;
        vx = (vx > 0.f) ? vx : expm1f(vx);
        vy = (vy > 0.f) ? vy : expm1f(vy);
        ((float2*)out)[d * 64 + lane] = make_float2(vx, vy);
    }
}

extern "C" void kernel_launch(void* const* d_in, const int* in_sizes, int n_in,
                              void* d_out, int out_size, void* d_ws, size_t ws_size,
                              hipStream_t stream) {
    const float* x     = (const float*)d_in[0];
    const int*   ei    = (const int*)d_in[1];
    const float* W     = (const float*)d_in[2];
    const float* att_s = (const float*)d_in[3];
    const float* att_d = (const float*)d_in[4];
    const float* bias  = (const float*)d_in[5];
    float* out = (float*)d_out;

    // workspace layout (~20 MB)
    unsigned int* h_bf = (unsigned int*)d_ws;                   // 12.8 MB
    float* asrc = (float*)(h_bf + (size_t)N_NODES * 64);        // 1.6 MB
    float* adst = asrc + (size_t)N_NODES * HEADS;               // 1.6 MB
    unsigned int* bin = (unsigned int*)(adst + (size_t)N_NODES * HEADS); // 391*2432*4 ≈ 3.8 MB
    int* cnt = (int*)(bin + (size_t)NBUCK * BCAP + 16);         // 391 ints (+pad before)

    hipMemsetAsync(cnt, 0, NBUCK * sizeof(int), stream);
    k_gemm_bin<<<(N_NODES + 63) / 64, 256, 0, stream>>>(x, W, att_s, att_d, ei,
                                                        h_bf, asrc, adst, cnt, bin);
    k_aggr_lds<<<NBUCK, 512, 0, stream>>>(h_bf, bin, cnt, asrc, adst, bias, out);
}

// Round 9
// 202.541 us; speedup vs baseline: 4.3561x; 4.3561x over previous
//
#include <hip/hip_runtime.h>
#include <hip/hip_bf16.h>

#define N_NODES 50000
#define N_EDGES 800000
#define HEADS 8
#define DIM 128
#define NEG_SLOPE 0.2f
#define EPS 1e-16f
#define NBUCK 391            // ceil(50000/128) buckets of 128 dst nodes
#define BCAP 2432            // bucket capacity (load ~Poisson(2048); +8.5 sigma)
#define BINB 160             // bin producer blocks
#define EPB (N_EDGES / BINB) // 5000 edges per bin block

// bf16x2 pack/unpack (RNE), exact unpack
__device__ inline unsigned int f2_to_bf2(float a, float b) {
    unsigned int ua = __float_as_uint(a);
    unsigned int ub = __float_as_uint(b);
    ua += 0x7fff + ((ua >> 16) & 1);
    ub += 0x7fff + ((ub >> 16) & 1);
    return (ua >> 16) | (ub & 0xffff0000u);
}
__device__ inline float2 bf2_to_f2(unsigned int u) {
    return make_float2(__uint_as_float(u << 16),
                       __uint_as_float(u & 0xffff0000u));
}

// ---------------------------------------------------------------------------
// Kernel 1: pure GEMM h = x@W (fp32), epilogue: per-node logits + bf16 pack.
// Also zeroes cnt[NBUCK] (first 2 blocks) — k_bin runs after, stream-ordered.
// ---------------------------------------------------------------------------
__global__ __launch_bounds__(256) void k_gemm(const float* __restrict__ x,
                                              const float* __restrict__ W,
                                              const float* __restrict__ att_s,
                                              const float* __restrict__ att_d,
                                              unsigned int* __restrict__ h_bf,
                                              float* __restrict__ asrc,
                                              float* __restrict__ adst,
                                              int* __restrict__ cnt) {
    constexpr int LDT = 68;
    __shared__ float xs[128 * LDT];
    const int row0 = blockIdx.x * 64;
    const int tid = threadIdx.x;

    const int gid = blockIdx.x * 256 + tid;
    if (gid < NBUCK) cnt[gid] = 0;

    for (int i = tid; i < 64 * 32; i += 256) {
        const int r = i >> 5;
        const int k4 = i & 31;
        const int row = row0 + r;
        float4 v = make_float4(0.f, 0.f, 0.f, 0.f);
        if (row < N_NODES) v = ((const float4*)x)[row * 32 + k4];
        const int k = k4 * 4;
        xs[(k + 0) * LDT + r] = v.x;
        xs[(k + 1) * LDT + r] = v.y;
        xs[(k + 2) * LDT + r] = v.z;
        xs[(k + 3) * LDT + r] = v.w;
    }
    __syncthreads();

    const int colg = tid & 31;
    const int rowg = tid >> 5;
    float acc[8][4];
#pragma unroll
    for (int r = 0; r < 8; ++r)
#pragma unroll
        for (int j = 0; j < 4; ++j) acc[r][j] = 0.f;

    for (int k = 0; k < 128; ++k) {
        const float4 w = ((const float4*)W)[k * 32 + colg];
        const float* xr = xs + k * LDT + rowg * 8;
        const float4 xa = *(const float4*)(xr);
        const float4 xb = *(const float4*)(xr + 4);
        const float xv[8] = {xa.x, xa.y, xa.z, xa.w, xb.x, xb.y, xb.z, xb.w};
        const float wv[4] = {w.x, w.y, w.z, w.w};
#pragma unroll
        for (int r = 0; r < 8; ++r)
#pragma unroll
            for (int j = 0; j < 4; ++j) acc[r][j] += xv[r] * wv[j];
    }

    const int hd = colg >> 2;
    const float4 asv = ((const float4*)att_s)[colg];
    const float4 adv = ((const float4*)att_d)[colg];
#pragma unroll
    for (int r = 0; r < 8; ++r) {
        const int row = row0 + rowg * 8 + r;
        float ps = acc[r][0] * asv.x + acc[r][1] * asv.y +
                   acc[r][2] * asv.z + acc[r][3] * asv.w;
        float pd = acc[r][0] * adv.x + acc[r][1] * adv.y +
                   acc[r][2] * adv.z + acc[r][3] * adv.w;
        ps += __shfl_xor(ps, 1); ps += __shfl_xor(ps, 2);
        pd += __shfl_xor(pd, 1); pd += __shfl_xor(pd, 2);
        if (row < N_NODES) {
            if ((colg & 3) == 0) {
                asrc[row * 8 + hd] = ps;
                adst[row * 8 + hd] = pd;
            }
            uint2 p;
            p.x = f2_to_bf2(acc[r][0], acc[r][1]);
            p.y = f2_to_bf2(acc[r][2], acc[r][3]);
            ((uint2*)h_bf)[row * 32 + colg] = p;
        }
    }
}

// ---------------------------------------------------------------------------
// Kernel 2: fat-block bucket binning. 160 blocks x 5000 edges. LDS counting
// sort by bucket, one global atomic per (block,bucket), contiguous run
// write-out. Record = (dst<<16)|src. bucket = rec>>23.
// NB: scan thread t<128 covers buckets 4t..4t+3 (0..511) — every access to
// the NBUCK-sized arrays MUST be guarded (round-8 crash: unguarded base/cur
// writes at b>=392 corrupted adjacent LDS arrays -> wild global writes).
// ---------------------------------------------------------------------------
__global__ __launch_bounds__(256) void k_bin(const int* __restrict__ ei,
                                             int* __restrict__ cnt,
                                             unsigned int* __restrict__ bin) {
    __shared__ unsigned int srt[EPB];     // 20 KB
    __shared__ int hist[NBUCK];
    __shared__ int base[NBUCK];
    __shared__ int cur[NBUCK];
    __shared__ int gbase[NBUCK];
    __shared__ int sums[128];
    const int tid = threadIdx.x;
    const int e0 = blockIdx.x * EPB;

    for (int b = tid; b < NBUCK; b += 256) hist[b] = 0;
    __syncthreads();

    // pass 1: histogram
    for (int i = tid; i < EPB; i += 256)
        atomicAdd(&hist[ei[N_EDGES + e0 + i] >> 7], 1);
    __syncthreads();

    // exclusive scan over NBUCK: thread t<128 owns buckets 4t..4t+3 (guarded!)
    int loc0 = 0, loc1 = 0, loc2 = 0, loc3 = 0, tot = 0;
    if (tid < 128) {
        const int b = tid * 4;
        loc0 = (b     < NBUCK) ? hist[b]     : 0;
        loc1 = (b + 1 < NBUCK) ? hist[b + 1] : 0;
        loc2 = (b + 2 < NBUCK) ? hist[b + 2] : 0;
        loc3 = (b + 3 < NBUCK) ? hist[b + 3] : 0;
        tot = loc0 + loc1 + loc2 + loc3;
        sums[tid] = tot;
    }
    __syncthreads();
    for (int off = 1; off < 128; off <<= 1) {
        int v = 0;
        if (tid < 128 && tid >= off) v = sums[tid - off];
        __syncthreads();
        if (tid < 128) sums[tid] += v;
        __syncthreads();
    }
    if (tid < 128) {
        int run = sums[tid] - tot;
        const int b = tid * 4;
        if (b     < NBUCK) { base[b]     = run; cur[b]     = run; } run += loc0;
        if (b + 1 < NBUCK) { base[b + 1] = run; cur[b + 1] = run; } run += loc1;
        if (b + 2 < NBUCK) { base[b + 2] = run; cur[b + 2] = run; } run += loc2;
        if (b + 3 < NBUCK) { base[b + 3] = run; cur[b + 3] = run; }
    }
    __syncthreads();

    // pass 2: scatter into sorted LDS
    for (int i = tid; i < EPB; i += 256) {
        const unsigned src = (unsigned)ei[e0 + i];
        const unsigned dst = (unsigned)ei[N_EDGES + e0 + i];
        const int p = atomicAdd(&cur[dst >> 7], 1);
        if ((unsigned)p < (unsigned)EPB) srt[p] = (dst << 16) | src;
    }
    __syncthreads();

    // reserve global ranges (one atomic per non-empty bucket)
    for (int b = tid; b < NBUCK; b += 256)
        gbase[b] = (hist[b] > 0) ? atomicAdd(&cnt[b], hist[b]) : 0;
    __syncthreads();

    // contiguous run copy-out
    for (int p = tid; p < EPB; p += 256) {
        const unsigned rec = srt[p];
        const int b = rec >> 23;
        if (b < NBUCK) {
            const int pos = gbase[b] + (p - base[b]);
            if ((unsigned)pos < (unsigned)BCAP)
                bin[(size_t)b * BCAP + pos] = rec;
        }
    }
}

// ---------------------------------------------------------------------------
// Kernel 3: aggregation. One block (8 waves) per bucket. LDS counting-sort
// the bucket's records by dlocal (128 keys, exactly sized arrays), then
// register accumulation: wave owns a node, depth-16 batched h_bf/asrc
// gathers, one coalesced out write. No atomics in the hot loop.
// ---------------------------------------------------------------------------
__global__ __launch_bounds__(512) void k_aggr(const unsigned int* __restrict__ h_bf,
                                              const unsigned int* __restrict__ bin,
                                              const int* __restrict__ cnt,
                                              const float* __restrict__ asrc,
                                              const float* __restrict__ adst,
                                              const float* __restrict__ bias,
                                              float* __restrict__ out) {
    __shared__ unsigned int srt[BCAP];    // 9.7 KB
    __shared__ int hist[128], base[128], cur[128], scn[128];

    const int bkt = blockIdx.x;
    const int tid = threadIdx.x;
    const int wid = tid >> 6;
    const int lane = tid & 63;
    const int hd = lane >> 3;

    const int cntb = min(cnt[bkt], BCAP);
    const unsigned int* seg = bin + (size_t)bkt * BCAP;

    if (tid < 128) hist[tid] = 0;
    __syncthreads();
    for (int i = tid; i < cntb; i += 512)
        atomicAdd(&hist[(seg[i] >> 16) & 127], 1);
    __syncthreads();
    if (tid < 128) scn[tid] = hist[tid];
    __syncthreads();
    for (int off = 1; off < 128; off <<= 1) {
        int v = 0;
        if (tid < 128 && tid >= off) v = scn[tid - off];
        __syncthreads();
        if (tid < 128) scn[tid] += v;
        __syncthreads();
    }
    if (tid < 128) {
        base[tid] = scn[tid] - hist[tid];
        cur[tid] = base[tid];
    }
    __syncthreads();
    for (int i = tid; i < cntb; i += 512) {
        const unsigned rec = seg[i];
        const int p = atomicAdd(&cur[(rec >> 16) & 127], 1);
        if ((unsigned)p < (unsigned)BCAP) srt[p] = rec;
    }
    __syncthreads();

    // per-wave node processing: wave wid handles dlocal = wid, wid+8, ...
    for (int dl = wid; dl < 128; dl += 8) {
        const int d = bkt * 128 + dl;
        if (d >= N_NODES) continue;
        const int jb = base[dl];
        const int jn = hist[dl];

        const float adst_h = adst[d * 8 + hd];
        const float asrc_self = asrc[d * 8 + hd];
        const float2 hdv = bf2_to_f2(h_bf[d * 64 + lane]);

        float es = asrc_self + adst_h;
        es = (es >= 0.f) ? es : NEG_SLOPE * es;
        const float exs = __expf(es);

        float2 acc = make_float2(0.f, 0.f);
        float den = 0.f;

        for (int j0 = 0; j0 < jn; j0 += 16) {
            int s[16];
#pragma unroll
            for (int i = 0; i < 16; ++i) {
                const int jj = j0 + i;
                s[i] = (int)(srt[jb + ((jj < jn) ? jj : jn - 1)] & 0xffffu);
            }
            unsigned int hv[16];
            float a[16];
#pragma unroll
            for (int i = 0; i < 16; ++i) {
                hv[i] = h_bf[s[i] * 64 + lane];
                a[i] = asrc[s[i] * 8 + hd];
            }
            const int rem = jn - j0;
#pragma unroll
            for (int i = 0; i < 16; ++i) {
                float e = a[i] + adst_h;
                e = (e >= 0.f) ? e : NEG_SLOPE * e;
                const float ex = (i < rem) ? __expf(e) : 0.f;
                const float2 hv2 = bf2_to_f2(hv[i]);
                acc.x += ex * hv2.x;
                acc.y += ex * hv2.y;
                den += ex;
            }
        }

        const float dtot = den + exs + EPS;
        const float2 b2 = ((const float2*)bias)[lane];
        float vx = (acc.x + exs * hdv.x) / dtot + b2.x;
        float vy = (acc.y + exs * hdv.y) / dtot + b2.y;
        vx = (vx > 0.f) ? vx : expm1f(vx);
        vy = (vy > 0.f) ? vy : expm1f(vy);
        ((float2*)out)[d * 64 + lane] = make_float2(vx, vy);
    }
}

extern "C" void kernel_launch(void* const* d_in, const int* in_sizes, int n_in,
                              void* d_out, int out_size, void* d_ws, size_t ws_size,
                              hipStream_t stream) {
    const float* x     = (const float*)d_in[0];
    const int*   ei    = (const int*)d_in[1];
    const float* W     = (const float*)d_in[2];
    const float* att_s = (const float*)d_in[3];
    const float* att_d = (const float*)d_in[4];
    const float* bias  = (const float*)d_in[5];
    float* out = (float*)d_out;

    // workspace layout (~20 MB)
    unsigned int* h_bf = (unsigned int*)d_ws;                   // 12.8 MB
    float* asrc = (float*)(h_bf + (size_t)N_NODES * 64);        // 1.6 MB
    float* adst = asrc + (size_t)N_NODES * HEADS;               // 1.6 MB
    unsigned int* bin = (unsigned int*)(adst + (size_t)N_NODES * HEADS); // 3.8 MB
    int* cnt = (int*)(bin + (size_t)NBUCK * BCAP);              // 391 ints

    k_gemm<<<(N_NODES + 63) / 64, 256, 0, stream>>>(x, W, att_s, att_d,
                                                    h_bf, asrc, adst, cnt);
    k_bin<<<BINB, 256, 0, stream>>>(ei, cnt, bin);
    k_aggr<<<NBUCK, 512, 0, stream>>>(h_bf, bin, cnt, asrc, adst, bias, out);
}

// Round 10
// 189.925 us; speedup vs baseline: 4.6454x; 1.0664x over previous
//
#include <hip/hip_runtime.h>
#include <hip/hip_bf16.h>

#define N_NODES 50000
#define N_EDGES 800000
#define HEADS 8
#define DIM 128
#define NEG_SLOPE 0.2f
#define EPS 1e-16f
#define NBUCK 782            // ceil(50000/64) buckets of 64 dst nodes
#define BNODES 64
#define BCAP 1312            // bucket capacity (load ~Poisson(1023); +9 sigma)
#define BINB 160             // bin producer blocks
#define EPB (N_EDGES / BINB) // 5000 edges per bin block

// bf16x2 pack/unpack (RNE), exact unpack
__device__ inline unsigned int f2_to_bf2(float a, float b) {
    unsigned int ua = __float_as_uint(a);
    unsigned int ub = __float_as_uint(b);
    ua += 0x7fff + ((ua >> 16) & 1);
    ub += 0x7fff + ((ub >> 16) & 1);
    return (ua >> 16) | (ub & 0xffff0000u);
}
__device__ inline float2 bf2_to_f2(unsigned int u) {
    return make_float2(__uint_as_float(u << 16),
                       __uint_as_float(u & 0xffff0000u));
}

// ---------------------------------------------------------------------------
// Kernel 1: pure GEMM h = x@W (fp32), epilogue: per-node logits + bf16 pack.
// Also zeroes cnt[NBUCK] (first 4 blocks' worth of gids).
// ---------------------------------------------------------------------------
__global__ __launch_bounds__(256) void k_gemm(const float* __restrict__ x,
                                              const float* __restrict__ W,
                                              const float* __restrict__ att_s,
                                              const float* __restrict__ att_d,
                                              unsigned int* __restrict__ h_bf,
                                              float* __restrict__ asrc,
                                              float* __restrict__ adst,
                                              int* __restrict__ cnt) {
    constexpr int LDT = 68;
    __shared__ float xs[128 * LDT];
    const int row0 = blockIdx.x * 64;
    const int tid = threadIdx.x;

    const int gid = blockIdx.x * 256 + tid;
    if (gid < NBUCK) cnt[gid] = 0;

    for (int i = tid; i < 64 * 32; i += 256) {
        const int r = i >> 5;
        const int k4 = i & 31;
        const int row = row0 + r;
        float4 v = make_float4(0.f, 0.f, 0.f, 0.f);
        if (row < N_NODES) v = ((const float4*)x)[row * 32 + k4];
        const int k = k4 * 4;
        xs[(k + 0) * LDT + r] = v.x;
        xs[(k + 1) * LDT + r] = v.y;
        xs[(k + 2) * LDT + r] = v.z;
        xs[(k + 3) * LDT + r] = v.w;
    }
    __syncthreads();

    const int colg = tid & 31;
    const int rowg = tid >> 5;
    float acc[8][4];
#pragma unroll
    for (int r = 0; r < 8; ++r)
#pragma unroll
        for (int j = 0; j < 4; ++j) acc[r][j] = 0.f;

    for (int k = 0; k < 128; ++k) {
        const float4 w = ((const float4*)W)[k * 32 + colg];
        const float* xr = xs + k * LDT + rowg * 8;
        const float4 xa = *(const float4*)(xr);
        const float4 xb = *(const float4*)(xr + 4);
        const float xv[8] = {xa.x, xa.y, xa.z, xa.w, xb.x, xb.y, xb.z, xb.w};
        const float wv[4] = {w.x, w.y, w.z, w.w};
#pragma unroll
        for (int r = 0; r < 8; ++r)
#pragma unroll
            for (int j = 0; j < 4; ++j) acc[r][j] += xv[r] * wv[j];
    }

    const int hd = colg >> 2;
    const float4 asv = ((const float4*)att_s)[colg];
    const float4 adv = ((const float4*)att_d)[colg];
#pragma unroll
    for (int r = 0; r < 8; ++r) {
        const int row = row0 + rowg * 8 + r;
        float ps = acc[r][0] * asv.x + acc[r][1] * asv.y +
                   acc[r][2] * asv.z + acc[r][3] * asv.w;
        float pd = acc[r][0] * adv.x + acc[r][1] * adv.y +
                   acc[r][2] * adv.z + acc[r][3] * adv.w;
        ps += __shfl_xor(ps, 1); ps += __shfl_xor(ps, 2);
        pd += __shfl_xor(pd, 1); pd += __shfl_xor(pd, 2);
        if (row < N_NODES) {
            if ((colg & 3) == 0) {
                asrc[row * 8 + hd] = ps;
                adst[row * 8 + hd] = pd;
            }
            uint2 p;
            p.x = f2_to_bf2(acc[r][0], acc[r][1]);
            p.y = f2_to_bf2(acc[r][2], acc[r][3]);
            ((uint2*)h_bf)[row * 32 + colg] = p;
        }
    }
}

// ---------------------------------------------------------------------------
// Kernel 2: fat-block bucket binning. 160 blocks x 5000 edges. LDS counting
// sort by 64-node bucket, one global atomic per (block,bucket), contiguous
// run write-out (~6.4 records/run). Record = (dst<<16)|src; bucket = rec>>22.
// All accesses to NBUCK-sized arrays guarded (round-8 lesson).
// ---------------------------------------------------------------------------
__global__ __launch_bounds__(256) void k_bin(const int* __restrict__ ei,
                                             int* __restrict__ cnt,
                                             unsigned int* __restrict__ bin) {
    __shared__ unsigned int srt[EPB];     // 20 KB
    __shared__ int hist[NBUCK];           // 3.1 KB each
    __shared__ int base[NBUCK];
    __shared__ int cur[NBUCK];
    __shared__ int gbase[NBUCK];
    __shared__ int sums[256];
    const int tid = threadIdx.x;
    const int e0 = blockIdx.x * EPB;

    for (int b = tid; b < NBUCK; b += 256) hist[b] = 0;
    __syncthreads();

    // pass 1: histogram (bucket = dst >> 6)
    for (int i = tid; i < EPB; i += 256)
        atomicAdd(&hist[ei[N_EDGES + e0 + i] >> 6], 1);
    __syncthreads();

    // exclusive scan: thread t owns buckets 4t..4t+3 (guarded; 4*256 >= NBUCK)
    int loc0 = 0, loc1 = 0, loc2 = 0, loc3 = 0, tot = 0;
    {
        const int b = tid * 4;
        loc0 = (b     < NBUCK) ? hist[b]     : 0;
        loc1 = (b + 1 < NBUCK) ? hist[b + 1] : 0;
        loc2 = (b + 2 < NBUCK) ? hist[b + 2] : 0;
        loc3 = (b + 3 < NBUCK) ? hist[b + 3] : 0;
        tot = loc0 + loc1 + loc2 + loc3;
        sums[tid] = tot;
    }
    __syncthreads();
    for (int off = 1; off < 256; off <<= 1) {
        const int v = (tid >= off) ? sums[tid - off] : 0;
        __syncthreads();
        sums[tid] += v;
        __syncthreads();
    }
    {
        int run = sums[tid] - tot;
        const int b = tid * 4;
        if (b     < NBUCK) { base[b]     = run; cur[b]     = run; } run += loc0;
        if (b + 1 < NBUCK) { base[b + 1] = run; cur[b + 1] = run; } run += loc1;
        if (b + 2 < NBUCK) { base[b + 2] = run; cur[b + 2] = run; } run += loc2;
        if (b + 3 < NBUCK) { base[b + 3] = run; cur[b + 3] = run; }
    }
    __syncthreads();

    // pass 2: scatter into sorted LDS
    for (int i = tid; i < EPB; i += 256) {
        const unsigned src = (unsigned)ei[e0 + i];
        const unsigned dst = (unsigned)ei[N_EDGES + e0 + i];
        const int p = atomicAdd(&cur[dst >> 6], 1);
        if ((unsigned)p < (unsigned)EPB) srt[p] = (dst << 16) | src;
    }
    __syncthreads();

    // reserve global ranges (one atomic per non-empty bucket)
    for (int b = tid; b < NBUCK; b += 256)
        gbase[b] = (hist[b] > 0) ? atomicAdd(&cnt[b], hist[b]) : 0;
    __syncthreads();

    // contiguous run copy-out
    for (int p = tid; p < EPB; p += 256) {
        const unsigned rec = srt[p];
        const int b = rec >> 22;
        if (b < NBUCK) {
            const int pos = gbase[b] + (p - base[b]);
            if ((unsigned)pos < (unsigned)BCAP)
                bin[(size_t)b * BCAP + pos] = rec;
        }
    }
}

// ---------------------------------------------------------------------------
// Kernel 3: aggregation. One block (8 waves, 512 thr) per 64-node bucket —
// 782 blocks => ~24 waves/CU (vs 391/24% occ in round 9). Single-pass LDS
// counting-sort (ranks kept in registers, <=3 records/thread), then register
// accumulation: wave owns a node (8 per wave), depth-16 batched gathers.
// ---------------------------------------------------------------------------
__global__ __launch_bounds__(512) void k_aggr(const unsigned int* __restrict__ h_bf,
                                              const unsigned int* __restrict__ bin,
                                              const int* __restrict__ cnt,
                                              const float* __restrict__ asrc,
                                              const float* __restrict__ adst,
                                              const float* __restrict__ bias,
                                              float* __restrict__ out) {
    __shared__ unsigned int srt[BCAP];    // 5.2 KB
    __shared__ int hist[BNODES], base[BNODES], scn[BNODES];

    const int bkt = blockIdx.x;
    const int tid = threadIdx.x;
    const int wid = tid >> 6;
    const int lane = tid & 63;
    const int hd = lane >> 3;

    const int cntb = min(cnt[bkt], BCAP);
    const unsigned int* seg = bin + (size_t)bkt * BCAP;

    if (tid < BNODES) hist[tid] = 0;
    __syncthreads();

    // single pass: read seg once, rank via LDS atomic, keep in registers
    unsigned int myrec[3];
    int myrank[3];
    int nrec = 0;
    for (int i = tid; i < cntb; i += 512) {
        const unsigned rec = seg[i];
        myrank[nrec] = atomicAdd(&hist[(rec >> 16) & 63], 1);
        myrec[nrec] = rec;
        ++nrec;
    }
    __syncthreads();

    if (tid < BNODES) scn[tid] = hist[tid];
    __syncthreads();
    for (int off = 1; off < BNODES; off <<= 1) {
        int v = 0;
        if (tid < BNODES && tid >= off) v = scn[tid - off];
        __syncthreads();
        if (tid < BNODES) scn[tid] += v;
        __syncthreads();
    }
    if (tid < BNODES) base[tid] = scn[tid] - hist[tid];
    __syncthreads();

    for (int k = 0; k < nrec; ++k) {
        const unsigned rec = myrec[k];
        const int p = base[(rec >> 16) & 63] + myrank[k];
        if ((unsigned)p < (unsigned)BCAP) srt[p] = rec;
    }
    __syncthreads();

    // per-wave node processing: wave wid handles dlocal = wid, wid+8, ...
    for (int dl = wid; dl < BNODES; dl += 8) {
        const int d = bkt * BNODES + dl;
        if (d >= N_NODES) continue;
        const int jb = base[dl];
        const int jn = hist[dl];

        const float adst_h = adst[d * 8 + hd];
        const float asrc_self = asrc[d * 8 + hd];
        const float2 hdv = bf2_to_f2(h_bf[d * 64 + lane]);

        float es = asrc_self + adst_h;
        es = (es >= 0.f) ? es : NEG_SLOPE * es;
        const float exs = __expf(es);

        float2 acc = make_float2(0.f, 0.f);
        float den = 0.f;

        for (int j0 = 0; j0 < jn; j0 += 16) {
            int s[16];
#pragma unroll
            for (int i = 0; i < 16; ++i) {
                const int jj = j0 + i;
                s[i] = (int)(srt[jb + ((jj < jn) ? jj : jn - 1)] & 0xffffu);
            }
            unsigned int hv[16];
            float a[16];
#pragma unroll
            for (int i = 0; i < 16; ++i) {
                hv[i] = h_bf[s[i] * 64 + lane];
                a[i] = asrc[s[i] * 8 + hd];
            }
            const int rem = jn - j0;
#pragma unroll
            for (int i = 0; i < 16; ++i) {
                float e = a[i] + adst_h;
                e = (e >= 0.f) ? e : NEG_SLOPE * e;
                const float ex = (i < rem) ? __expf(e) : 0.f;
                const float2 hv2 = bf2_to_f2(hv[i]);
                acc.x += ex * hv2.x;
                acc.y += ex * hv2.y;
                den += ex;
            }
        }

        const float dtot = den + exs + EPS;
        const float2 b2 = ((const float2*)bias)[lane];
        float vx = (acc.x + exs * hdv.x) / dtot + b2.x;
        float vy = (acc.y + exs * hdv.y) / dtot + b2.y;
        vx = (vx > 0.f) ? vx : expm1f(vx);
        vy = (vy > 0.f) ? vy : expm1f(vy);
        ((float2*)out)[d * 64 + lane] = make_float2(vx, vy);
    }
}

extern "C" void kernel_launch(void* const* d_in, const int* in_sizes, int n_in,
                              void* d_out, int out_size, void* d_ws, size_t ws_size,
                              hipStream_t stream) {
    const float* x     = (const float*)d_in[0];
    const int*   ei    = (const int*)d_in[1];
    const float* W     = (const float*)d_in[2];
    const float* att_s = (const float*)d_in[3];
    const float* att_d = (const float*)d_in[4];
    const float* bias  = (const float*)d_in[5];
    float* out = (float*)d_out;

    // workspace layout (~20.2 MB)
    unsigned int* h_bf = (unsigned int*)d_ws;                   // 12.8 MB
    float* asrc = (float*)(h_bf + (size_t)N_NODES * 64);        // 1.6 MB
    float* adst = asrc + (size_t)N_NODES * HEADS;               // 1.6 MB
    unsigned int* bin = (unsigned int*)(adst + (size_t)N_NODES * HEADS); // 4.1 MB
    int* cnt = (int*)(bin + (size_t)NBUCK * BCAP);              // 782 ints

    k_gemm<<<(N_NODES + 63) / 64, 256, 0, stream>>>(x, W, att_s, att_d,
                                                    h_bf, asrc, adst, cnt);
    k_bin<<<BINB, 256, 0, stream>>>(ei, cnt, bin);
    k_aggr<<<NBUCK, 512, 0, stream>>>(h_bf, bin, cnt, asrc, adst, bias, out);
}